// Round 1
// baseline (638.986 us; speedup 1.0000x reference)
//
#include <hip/hip_runtime.h>
#include <hip/hip_bf16.h>

#define NN 8192
#define DD 128

typedef __attribute__((ext_vector_type(8))) short short8;
typedef __attribute__((ext_vector_type(4))) float f32x4;

__device__ __forceinline__ unsigned short f2bf(float x) {
    unsigned u = __float_as_uint(x);
    u += 0x7FFFu + ((u >> 16) & 1u);   // round-to-nearest-even
    return (unsigned short)(u >> 16);
}
__device__ __forceinline__ float bf2f(unsigned short b) {
    return __uint_as_float(((unsigned)b) << 16);
}

// Cast emb -> bf16 (ws) and compute row sq-norms FROM THE BF16 VALUES
// (consistency with the MFMA dot products; diagonal ~ exactly 0).
__global__ void prep_kernel(const float* __restrict__ emb,
                            unsigned short* __restrict__ ebf,
                            float* __restrict__ nrm) {
    int row  = blockIdx.x * 4 + (threadIdx.x >> 6);   // 1 wave per row
    int lane = threadIdx.x & 63;
    const float2 v = *reinterpret_cast<const float2*>(emb + (size_t)row * DD + lane * 2);
    unsigned short b0 = f2bf(v.x), b1 = f2bf(v.y);
    ushort2 st; st.x = b0; st.y = b1;
    *reinterpret_cast<ushort2*>(ebf + (size_t)row * DD + lane * 2) = st;
    float f0 = bf2f(b0), f1 = bf2f(b1);
    float s = f0 * f0 + f1 * f1;
    #pragma unroll
    for (int m = 32; m; m >>= 1) s += __shfl_xor(s, m);
    if (lane == 0) nrm[row] = s;
}

// Block tile: 128 rows (i) x 256 cols (j). 8 waves in 2x4, each wave 64x64.
// Fragments loaded directly from global (emb_bf16 is 2 MB -> L2 resident).
__global__ __launch_bounds__(512)
void gram_kernel(const unsigned short* __restrict__ ebf,
                 const float* __restrict__ nrm,
                 const float* __restrict__ W,
                 double* __restrict__ accum,          // [0]=sumW [1]=sumDW
                 unsigned int* __restrict__ maxb) {
    const int wave = threadIdx.x >> 6;
    const int lane = threadIdx.x & 63;
    const int wRow = wave >> 2;          // 0..1
    const int wCol = wave & 3;           // 0..3
    const int i0 = blockIdx.y * 128 + wRow * 64;
    const int j0 = blockIdx.x * 256 + wCol * 64;

    const int lr = lane & 15;            // row (A) / col (B) within fragment
    const int lk = (lane >> 4) * 8;      // k offset within 32-chunk

    f32x4 acc[4][4];
    #pragma unroll
    for (int m = 0; m < 4; ++m)
        #pragma unroll
        for (int n = 0; n < 4; ++n) acc[m][n] = (f32x4){0.f, 0.f, 0.f, 0.f};

    #pragma unroll
    for (int kc = 0; kc < 4; ++kc) {     // K = 128 in chunks of 32
        short8 af[4], bf[4];
        #pragma unroll
        for (int m = 0; m < 4; ++m)
            af[m] = *reinterpret_cast<const short8*>(
                ebf + (size_t)(i0 + m * 16 + lr) * DD + kc * 32 + lk);
        #pragma unroll
        for (int n = 0; n < 4; ++n)
            bf[n] = *reinterpret_cast<const short8*>(
                ebf + (size_t)(j0 + n * 16 + lr) * DD + kc * 32 + lk);
        #pragma unroll
        for (int m = 0; m < 4; ++m)
            #pragma unroll
            for (int n = 0; n < 4; ++n)
                acc[m][n] = __builtin_amdgcn_mfma_f32_16x16x32_bf16(
                    af[m], bf[n], acc[m][n], 0, 0, 0);
    }

    // Epilogue: dist = sqrt(max(0, ni + nj - 2*dot)); stream W once.
    float nj[4];
    #pragma unroll
    for (int n = 0; n < 4; ++n) nj[n] = nrm[j0 + n * 16 + lr];

    float sW = 0.f, sDW = 0.f, dmax = 0.f;
    #pragma unroll
    for (int m = 0; m < 4; ++m) {
        const int giBase = i0 + m * 16 + (lane >> 4) * 4;
        #pragma unroll
        for (int r = 0; r < 4; ++r) {
            const int gi = giBase + r;
            const float ni = nrm[gi];
            const float* wrow = W + (size_t)gi * NN;
            #pragma unroll
            for (int n = 0; n < 4; ++n) {
                const int gj = j0 + n * 16 + lr;
                float sq = ni + nj[n] - 2.0f * acc[m][n][r];
                sq = fmaxf(sq, 0.0f);
                float d = sqrtf(sq);
                float w = wrow[gj];
                sW  += w;
                sDW += w * d;
                dmax = fmaxf(dmax, d);
            }
        }
    }

    #pragma unroll
    for (int m = 32; m; m >>= 1) {
        sW  += __shfl_xor(sW, m);
        sDW += __shfl_xor(sDW, m);
        dmax = fmaxf(dmax, __shfl_xor(dmax, m));
    }
    if (lane == 0) {
        atomicAdd(&accum[0], (double)sW);
        atomicAdd(&accum[1], (double)sDW);
        atomicMax(maxb, __float_as_uint(dmax));
    }
}

__global__ void finalize_kernel(const double* __restrict__ accum,
                                const unsigned int* __restrict__ maxb,
                                float* __restrict__ out) {
    double M = (double)__uint_as_float(*maxb);
    double loss = (accum[0] - accum[1] / M) / ((double)NN * (double)NN);
    out[0] = (float)loss;
}

extern "C" void kernel_launch(void* const* d_in, const int* in_sizes, int n_in,
                              void* d_out, int out_size, void* d_ws, size_t ws_size,
                              hipStream_t stream) {
    const float* emb = (const float*)d_in[0];
    const float* W   = (const float*)d_in[1];
    float* out = (float*)d_out;

    char* ws = (char*)d_ws;
    double* accum       = (double*)ws;                         // 16 B
    unsigned int* maxb  = (unsigned int*)(ws + 16);            // 4 B
    unsigned short* ebf = (unsigned short*)(ws + 32);          // 2 MB bf16 emb
    float* nrm          = (float*)(ws + 32 + (size_t)NN * DD * 2); // 32 KB norms

    hipMemsetAsync(d_ws, 0, 32, stream);
    prep_kernel<<<NN / 4, 256, 0, stream>>>(emb, ebf, nrm);
    dim3 grid(NN / 256, NN / 128);
    gram_kernel<<<grid, 512, 0, stream>>>(ebf, nrm, W, accum, maxb);
    finalize_kernel<<<1, 1, 0, stream>>>(accum, maxb, out);
}

// Round 2
// 149.816 us; speedup vs baseline: 4.2651x; 4.2651x over previous
//
#include <hip/hip_runtime.h>
#include <hip/hip_bf16.h>

#define NN 8192
#define DD 128

typedef __attribute__((ext_vector_type(8))) short short8;
typedef __attribute__((ext_vector_type(4))) float f32x4;

__device__ __forceinline__ unsigned short f2bf(float x) {
    unsigned u = __float_as_uint(x);
    u += 0x7FFFu + ((u >> 16) & 1u);   // round-to-nearest-even
    return (unsigned short)(u >> 16);
}
__device__ __forceinline__ float bf2f(unsigned short b) {
    return __uint_as_float(((unsigned)b) << 16);
}

// Cast emb -> bf16 (ws) and compute row sq-norms FROM THE BF16 VALUES
// (consistency with the MFMA dot products; diagonal ~ exactly 0).
__global__ void prep_kernel(const float* __restrict__ emb,
                            unsigned short* __restrict__ ebf,
                            float* __restrict__ nrm) {
    int row  = blockIdx.x * 4 + (threadIdx.x >> 6);   // 1 wave per row
    int lane = threadIdx.x & 63;
    const float2 v = *reinterpret_cast<const float2*>(emb + (size_t)row * DD + lane * 2);
    unsigned short b0 = f2bf(v.x), b1 = f2bf(v.y);
    ushort2 st; st.x = b0; st.y = b1;
    *reinterpret_cast<ushort2*>(ebf + (size_t)row * DD + lane * 2) = st;
    float f0 = bf2f(b0), f1 = bf2f(b1);
    float s = f0 * f0 + f1 * f1;
    #pragma unroll
    for (int m = 32; m; m >>= 1) s += __shfl_xor(s, m);
    if (lane == 0) nrm[row] = s;
}

// Block tile: 128 rows (i) x 256 cols (j). 8 waves in 2x4, each wave 64x64.
// Fragments loaded directly from global (emb_bf16 is 2 MB -> L2/L3 resident).
// Epilogue pairs acc with W^T via float4 loads (valid since dist is symmetric),
// reduces block-locally, stores ONE float4 partial per block (no atomics).
__global__ __launch_bounds__(512)
void gram_kernel(const unsigned short* __restrict__ ebf,
                 const float* __restrict__ nrm,
                 const float* __restrict__ W,
                 float4* __restrict__ part) {
    const int wave = threadIdx.x >> 6;
    const int lane = threadIdx.x & 63;
    const int wRow = wave >> 2;          // 0..1
    const int wCol = wave & 3;           // 0..3
    const int i0 = blockIdx.y * 128 + wRow * 64;
    const int j0 = blockIdx.x * 256 + wCol * 64;

    const int lr = lane & 15;            // row (A) / col (B) within fragment
    const int hi = lane >> 4;
    const int lk = hi * 8;               // k offset within 32-chunk

    f32x4 acc[4][4];
    #pragma unroll
    for (int m = 0; m < 4; ++m)
        #pragma unroll
        for (int n = 0; n < 4; ++n) acc[m][n] = (f32x4){0.f, 0.f, 0.f, 0.f};

    #pragma unroll
    for (int kc = 0; kc < 4; ++kc) {     // K = 128 in chunks of 32
        short8 af[4], bf[4];
        #pragma unroll
        for (int m = 0; m < 4; ++m)
            af[m] = *reinterpret_cast<const short8*>(
                ebf + (size_t)(i0 + m * 16 + lr) * DD + kc * 32 + lk);
        #pragma unroll
        for (int n = 0; n < 4; ++n)
            bf[n] = *reinterpret_cast<const short8*>(
                ebf + (size_t)(j0 + n * 16 + lr) * DD + kc * 32 + lk);
        #pragma unroll
        for (int m = 0; m < 4; ++m)
            #pragma unroll
            for (int n = 0; n < 4; ++n)
                acc[m][n] = __builtin_amdgcn_mfma_f32_16x16x32_bf16(
                    af[m], bf[n], acc[m][n], 0, 0, 0);
    }

    // acc[m][n][r] = dot(e_gi, e_gj), gi = i0+m*16+hi*4+r (4 CONSECUTIVE rows),
    // gj = j0+n*16+lr. Pair with W[gj][gi..gi+3] (== W^T) via float4.
    float nj[4];
    #pragma unroll
    for (int n = 0; n < 4; ++n) nj[n] = nrm[j0 + n * 16 + lr];

    float sW = 0.f, sDW = 0.f, dmax = 0.f;
    #pragma unroll
    for (int m = 0; m < 4; ++m) {
        const int giB = i0 + m * 16 + hi * 4;
        const f32x4 ni4 = *reinterpret_cast<const f32x4*>(nrm + giB);
        #pragma unroll
        for (int n = 0; n < 4; ++n) {
            const int gj = j0 + n * 16 + lr;
            const f32x4 w4 = *reinterpret_cast<const f32x4*>(
                W + (size_t)gj * NN + giB);
            #pragma unroll
            for (int r = 0; r < 4; ++r) {
                float sq = ni4[r] + nj[n] - 2.0f * acc[m][n][r];
                sq = fmaxf(sq, 0.0f);
                float d = sqrtf(sq);
                sW  += w4[r];
                sDW += w4[r] * d;
                dmax = fmaxf(dmax, d);
            }
        }
    }

    #pragma unroll
    for (int m = 32; m; m >>= 1) {
        sW  += __shfl_xor(sW, m);
        sDW += __shfl_xor(sDW, m);
        dmax = fmaxf(dmax, __shfl_xor(dmax, m));
    }

    __shared__ float sw_s[8], sdw_s[8], dm_s[8];
    if (lane == 0) { sw_s[wave] = sW; sdw_s[wave] = sDW; dm_s[wave] = dmax; }
    __syncthreads();
    if (threadIdx.x == 0) {
        float SW = 0.f, SDW = 0.f, DM = 0.f;
        #pragma unroll
        for (int k = 0; k < 8; ++k) {
            SW += sw_s[k]; SDW += sdw_s[k]; DM = fmaxf(DM, dm_s[k]);
        }
        float4 p; p.x = SW; p.y = SDW; p.z = DM; p.w = 0.f;
        part[blockIdx.y * gridDim.x + blockIdx.x] = p;
    }
}

// Single block: reduce 2048 per-block partials in fp64, emit the loss.
__global__ __launch_bounds__(512)
void reduce_kernel(const float4* __restrict__ part, int nblk,
                   float* __restrict__ out) {
    const int tid = threadIdx.x;
    double sW = 0.0, sDW = 0.0;
    float dmax = 0.f;
    for (int idx = tid; idx < nblk; idx += 512) {
        float4 p = part[idx];
        sW += (double)p.x; sDW += (double)p.y; dmax = fmaxf(dmax, p.z);
    }
    #pragma unroll
    for (int m = 32; m; m >>= 1) {
        sW  += __shfl_xor(sW, m);
        sDW += __shfl_xor(sDW, m);
        dmax = fmaxf(dmax, __shfl_xor(dmax, m));
    }
    __shared__ double sw_s[8], sdw_s[8];
    __shared__ float dm_s[8];
    const int w = tid >> 6, l = tid & 63;
    if (l == 0) { sw_s[w] = sW; sdw_s[w] = sDW; dm_s[w] = dmax; }
    __syncthreads();
    if (tid == 0) {
        double SW = 0.0, SDW = 0.0; float DM = 0.f;
        #pragma unroll
        for (int k = 0; k < 8; ++k) {
            SW += sw_s[k]; SDW += sdw_s[k]; DM = fmaxf(DM, dm_s[k]);
        }
        out[0] = (float)((SW - SDW / (double)DM) / ((double)NN * (double)NN));
    }
}

extern "C" void kernel_launch(void* const* d_in, const int* in_sizes, int n_in,
                              void* d_out, int out_size, void* d_ws, size_t ws_size,
                              hipStream_t stream) {
    const float* emb = (const float*)d_in[0];
    const float* W   = (const float*)d_in[1];
    float* out = (float*)d_out;

    char* ws = (char*)d_ws;
    float4* part        = (float4*)ws;                              // 32 KB (2048 x 16B)
    unsigned short* ebf = (unsigned short*)(ws + 32768);            // 2 MB bf16 emb
    float* nrm          = (float*)(ws + 32768 + (size_t)NN * DD * 2); // 32 KB norms

    prep_kernel<<<NN / 4, 256, 0, stream>>>(emb, ebf, nrm);
    dim3 grid(NN / 256, NN / 128);
    gram_kernel<<<grid, 512, 0, stream>>>(ebf, nrm, W, part);
    reduce_kernel<<<1, 512, 0, stream>>>(part, grid.x * grid.y, out);
}

// Round 3
// 107.847 us; speedup vs baseline: 5.9249x; 1.3892x over previous
//
#include <hip/hip_runtime.h>
#include <hip/hip_bf16.h>

#define NN 8192
#define DD 128

typedef __attribute__((ext_vector_type(8))) short short8;
typedef __attribute__((ext_vector_type(4))) float f32x4;

__device__ __forceinline__ unsigned short f2bf(float x) {
    unsigned u = __float_as_uint(x);
    u += 0x7FFFu + ((u >> 16) & 1u);   // round-to-nearest-even
    return (unsigned short)(u >> 16);
}
__device__ __forceinline__ float bf2f(unsigned short b) {
    return __uint_as_float(((unsigned)b) << 16);
}

// Cast emb -> bf16 (ws) and compute row sq-norms FROM THE BF16 VALUES.
__global__ void prep_kernel(const float* __restrict__ emb,
                            unsigned short* __restrict__ ebf,
                            float* __restrict__ nrm) {
    int row  = blockIdx.x * 4 + (threadIdx.x >> 6);   // 1 wave per row
    int lane = threadIdx.x & 63;
    const float2 v = *reinterpret_cast<const float2*>(emb + (size_t)row * DD + lane * 2);
    unsigned short b0 = f2bf(v.x), b1 = f2bf(v.y);
    ushort2 st; st.x = b0; st.y = b1;
    *reinterpret_cast<ushort2*>(ebf + (size_t)row * DD + lane * 2) = st;
    float f0 = bf2f(b0), f1 = bf2f(b1);
    float s = f0 * f0 + f1 * f1;
    #pragma unroll
    for (int m = 32; m; m >>= 1) s += __shfl_xor(s, m);
    if (lane == 0) nrm[row] = s;
}

// Block tile: 128x128, 4 waves (2x2), each wave 64x64.
// MFMA over K=128; epilogue pairs acc with W^T float4 (dist is symmetric).
// All 16 W loads issued as ONE batch (pinned by sched_barrier) before the
// last MFMA chunk -> ~4KB/wave in flight, latency hidden under MFMA + TLP.
__global__ __launch_bounds__(256)
void gram_kernel(const unsigned short* __restrict__ ebf,
                 const float* __restrict__ nrm,
                 const float* __restrict__ W,
                 float4* __restrict__ part) {
    const int wave = threadIdx.x >> 6;
    const int lane = threadIdx.x & 63;
    const int wRow = wave >> 1;          // 0..1
    const int wCol = wave & 1;           // 0..1
    const int i0 = blockIdx.y * 128 + wRow * 64;
    const int j0 = blockIdx.x * 128 + wCol * 64;

    const int lr = lane & 15;            // row (A) / col (B) within fragment
    const int hi = lane >> 4;
    const int lk = hi * 8;               // k offset within 32-chunk

    f32x4 acc[4][4];
    #pragma unroll
    for (int m = 0; m < 4; ++m)
        #pragma unroll
        for (int n = 0; n < 4; ++n) acc[m][n] = (f32x4){0.f, 0.f, 0.f, 0.f};

    short8 af[4], bf[4];
    // K chunks 0..2: stage + MFMA (compiler-scheduled)
    #pragma unroll
    for (int kc = 0; kc < 3; ++kc) {
        #pragma unroll
        for (int m = 0; m < 4; ++m)
            af[m] = *reinterpret_cast<const short8*>(
                ebf + (size_t)(i0 + m * 16 + lr) * DD + kc * 32 + lk);
        #pragma unroll
        for (int n = 0; n < 4; ++n)
            bf[n] = *reinterpret_cast<const short8*>(
                ebf + (size_t)(j0 + n * 16 + lr) * DD + kc * 32 + lk);
        #pragma unroll
        for (int m = 0; m < 4; ++m)
            #pragma unroll
            for (int n = 0; n < 4; ++n)
                acc[m][n] = __builtin_amdgcn_mfma_f32_16x16x32_bf16(
                    af[m], bf[n], acc[m][n], 0, 0, 0);
    }
    // K chunk 3: stage fragments first...
    #pragma unroll
    for (int m = 0; m < 4; ++m)
        af[m] = *reinterpret_cast<const short8*>(
            ebf + (size_t)(i0 + m * 16 + lr) * DD + 3 * 32 + lk);
    #pragma unroll
    for (int n = 0; n < 4; ++n)
        bf[n] = *reinterpret_cast<const short8*>(
            ebf + (size_t)(j0 + n * 16 + lr) * DD + 3 * 32 + lk);

    __builtin_amdgcn_sched_barrier(0);   // fence A: keep W batch below here

    // ...then issue the ENTIRE W^T batch + norms (older ebf loads complete
    // at vmcnt(16+), so MFMA kc3 runs while these 16 stream from HBM).
    float nj[4];
    #pragma unroll
    for (int n = 0; n < 4; ++n) nj[n] = nrm[j0 + n * 16 + lr];
    f32x4 ni4[4];
    #pragma unroll
    for (int m = 0; m < 4; ++m)
        ni4[m] = *reinterpret_cast<const f32x4*>(nrm + i0 + m * 16 + hi * 4);

    f32x4 w4[4][4];                      // [n][m]
    #pragma unroll
    for (int n = 0; n < 4; ++n) {
        const float* wb = W + (size_t)(j0 + n * 16 + lr) * NN + i0 + hi * 4;
        #pragma unroll
        for (int m = 0; m < 4; ++m)
            w4[n][m] = *reinterpret_cast<const f32x4*>(wb + m * 16);
    }

    __builtin_amdgcn_sched_barrier(0);   // fence B: don't sink loads below

    #pragma unroll
    for (int m = 0; m < 4; ++m)
        #pragma unroll
        for (int n = 0; n < 4; ++n)
            acc[m][n] = __builtin_amdgcn_mfma_f32_16x16x32_bf16(
                af[m], bf[n], acc[m][n], 0, 0, 0);

    // Consume: dist = sqrt(max(0, ni + nj - 2*dot)) paired with W^T.
    float sW = 0.f, sDW = 0.f, dmax = 0.f;
    #pragma unroll
    for (int m = 0; m < 4; ++m) {
        #pragma unroll
        for (int n = 0; n < 4; ++n) {
            #pragma unroll
            for (int r = 0; r < 4; ++r) {
                float sq = ni4[m][r] + nj[n] - 2.0f * acc[m][n][r];
                sq = fmaxf(sq, 0.0f);
                float d = sqrtf(sq);
                sW  += w4[n][m][r];
                sDW += w4[n][m][r] * d;
                dmax = fmaxf(dmax, d);
            }
        }
    }

    #pragma unroll
    for (int m = 32; m; m >>= 1) {
        sW  += __shfl_xor(sW, m);
        sDW += __shfl_xor(sDW, m);
        dmax = fmaxf(dmax, __shfl_xor(dmax, m));
    }

    __shared__ float sw_s[4], sdw_s[4], dm_s[4];
    if (lane == 0) { sw_s[wave] = sW; sdw_s[wave] = sDW; dm_s[wave] = dmax; }
    __syncthreads();
    if (threadIdx.x == 0) {
        float SW = 0.f, SDW = 0.f, DM = 0.f;
        #pragma unroll
        for (int k = 0; k < 4; ++k) {
            SW += sw_s[k]; SDW += sdw_s[k]; DM = fmaxf(DM, dm_s[k]);
        }
        float4 p; p.x = SW; p.y = SDW; p.z = DM; p.w = 0.f;
        part[blockIdx.y * gridDim.x + blockIdx.x] = p;
    }
}

// Single block: reduce per-block partials in fp64, emit the loss.
__global__ __launch_bounds__(512)
void reduce_kernel(const float4* __restrict__ part, int nblk,
                   float* __restrict__ out) {
    const int tid = threadIdx.x;
    double sW = 0.0, sDW = 0.0;
    float dmax = 0.f;
    for (int idx = tid; idx < nblk; idx += 512) {
        float4 p = part[idx];
        sW += (double)p.x; sDW += (double)p.y; dmax = fmaxf(dmax, p.z);
    }
    #pragma unroll
    for (int m = 32; m; m >>= 1) {
        sW  += __shfl_xor(sW, m);
        sDW += __shfl_xor(sDW, m);
        dmax = fmaxf(dmax, __shfl_xor(dmax, m));
    }
    __shared__ double sw_s[8], sdw_s[8];
    __shared__ float dm_s[8];
    const int w = tid >> 6, l = tid & 63;
    if (l == 0) { sw_s[w] = sW; sdw_s[w] = sDW; dm_s[w] = dmax; }
    __syncthreads();
    if (tid == 0) {
        double SW = 0.0, SDW = 0.0; float DM = 0.f;
        #pragma unroll
        for (int k = 0; k < 8; ++k) {
            SW += sw_s[k]; SDW += sdw_s[k]; DM = fmaxf(DM, dm_s[k]);
        }
        out[0] = (float)((SW - SDW / (double)DM) / ((double)NN * (double)NN));
    }
}

extern "C" void kernel_launch(void* const* d_in, const int* in_sizes, int n_in,
                              void* d_out, int out_size, void* d_ws, size_t ws_size,
                              hipStream_t stream) {
    const float* emb = (const float*)d_in[0];
    const float* W   = (const float*)d_in[1];
    float* out = (float*)d_out;

    char* ws = (char*)d_ws;
    float4* part        = (float4*)ws;                              // 64 KB (4096 x 16B)
    unsigned short* ebf = (unsigned short*)(ws + 65536);            // 2 MB bf16 emb
    float* nrm          = (float*)(ws + 65536 + (size_t)NN * DD * 2); // 32 KB norms

    prep_kernel<<<NN / 4, 256, 0, stream>>>(emb, ebf, nrm);
    dim3 grid(NN / 128, NN / 128);
    gram_kernel<<<grid, 256, 0, stream>>>(ebf, nrm, W, part);
    reduce_kernel<<<1, 512, 0, stream>>>(part, grid.x * grid.y, out);
}

// Round 4
// 83.545 us; speedup vs baseline: 7.6484x; 1.2909x over previous
//
#include <hip/hip_runtime.h>
#include <hip/hip_bf16.h>

#define NN 8192
#define DD 128
#define JTPB 16   // j-tiles (64 wide) per block

typedef __attribute__((ext_vector_type(8))) short short8;
typedef __attribute__((ext_vector_type(4))) float f32x4;

__device__ __forceinline__ unsigned short f2bf(float x) {
    unsigned u = __float_as_uint(x);
    u += 0x7FFFu + ((u >> 16) & 1u);   // round-to-nearest-even
    return (unsigned short)(u >> 16);
}
__device__ __forceinline__ float bf2f(unsigned short b) {
    return __uint_as_float(((unsigned)b) << 16);
}

__device__ __forceinline__ void gld_lds16(const float* src, float* ldst) {
    __builtin_amdgcn_global_load_lds(
        (const __attribute__((address_space(1))) void*)src,
        (__attribute__((address_space(3))) void*)ldst, 16, 0, 0);
}

// Cast emb -> bf16 (ws) and compute row sq-norms FROM THE BF16 VALUES.
__global__ void prep_kernel(const float* __restrict__ emb,
                            unsigned short* __restrict__ ebf,
                            float* __restrict__ nrm) {
    int row  = blockIdx.x * 4 + (threadIdx.x >> 6);   // 1 wave per row
    int lane = threadIdx.x & 63;
    const float2 v = *reinterpret_cast<const float2*>(emb + (size_t)row * DD + lane * 2);
    unsigned short b0 = f2bf(v.x), b1 = f2bf(v.y);
    ushort2 st; st.x = b0; st.y = b1;
    *reinterpret_cast<ushort2*>(ebf + (size_t)row * DD + lane * 2) = st;
    float f0 = bf2f(b0), f1 = bf2f(b1);
    float s = f0 * f0 + f1 * f1;
    #pragma unroll
    for (int m = 32; m; m >>= 1) s += __shfl_xor(s, m);
    if (lane == 0) nrm[row] = s;
}

// Persistent block: i-tile fixed (128 rows), strides over 16 j-tiles (64 each).
// W staged row-major -> LDS via global_load_lds (coalesced 512B/row segments,
// chunk-XOR swizzle inside 128B windows), double-buffered, prefetched one
// tile ahead. Epilogue reads W^T from LDS (bank-even b128), pairs with MFMA
// acc: dist = sqrt(max(0, ni + nj - 2*dot)). No atomics; 1 partial per block.
__global__ __launch_bounds__(256)
void gram_kernel(const unsigned short* __restrict__ ebf,
                 const float* __restrict__ nrm,
                 const float* __restrict__ W,
                 float4* __restrict__ part) {
    __shared__ float wlds[2][64 * 128];   // 2 x 32 KB W tiles
    __shared__ float sw_s[4], sdw_s[4], dm_s[4];

    const int wave = threadIdx.x >> 6;
    const int lane = threadIdx.x & 63;
    const int wRow = wave >> 1;          // 0..1 : i half (64 rows)
    const int wCol = wave & 1;           // 0..1 : j half (32 cols)
    const int i0  = blockIdx.y * 128;
    const int jc0 = blockIdx.x * (JTPB * 64);

    const int lr = lane & 15;
    const int hi = lane >> 4;
    const int lk = hi * 8;

    // Prefetch-lane coords: slot q = r*256 + tid -> row j'=q>>5, slot c=q&31.
    // Source chunk = c ^ (j'&7)  (involution within a 128B window).
    int pj[8], pc[8];
    #pragma unroll
    for (int r = 0; r < 8; ++r) {
        int q = r * 256 + (int)threadIdx.x;
        int jrow = q >> 5;
        pj[r] = jrow;
        pc[r] = ((q & 31) ^ (jrow & 7)) * 4;
    }

    // A fragments (this block's 128 i-rows) cached for all iterations.
    short8 af[4][4];   // [kc][m]
    #pragma unroll
    for (int kc = 0; kc < 4; ++kc)
        #pragma unroll
        for (int m = 0; m < 4; ++m)
            af[kc][m] = *reinterpret_cast<const short8*>(
                ebf + (size_t)(i0 + wRow * 64 + m * 16 + lr) * DD + kc * 32 + lk);
    f32x4 ni4[4];
    #pragma unroll
    for (int m = 0; m < 4; ++m)
        ni4[m] = *reinterpret_cast<const f32x4*>(nrm + i0 + wRow * 64 + m * 16 + hi * 4);

    __builtin_amdgcn_sched_barrier(0);
    // Prologue: prefetch tile 0 -> buf 0.
    #pragma unroll
    for (int r = 0; r < 8; ++r)
        gld_lds16(W + (size_t)(jc0 + pj[r]) * NN + i0 + pc[r],
                  &wlds[0][r * 1024 + wave * 256]);
    __syncthreads();

    float sW = 0.f, sDW = 0.f, dmax = 0.f;

    for (int t = 0; t < JTPB; ++t) {
        const int j0t = jc0 + t * 64;
        const int jw  = j0t + wCol * 32;
        const int cb  = t & 1;

        // B fragments + col norms for THIS tile — issued BEFORE the prefetch
        // so their vmcnt wait does not drain the prefetch (in-order counter).
        short8 bf[4][2];
        #pragma unroll
        for (int kc = 0; kc < 4; ++kc)
            #pragma unroll
            for (int n = 0; n < 2; ++n)
                bf[kc][n] = *reinterpret_cast<const short8*>(
                    ebf + (size_t)(jw + n * 16 + lr) * DD + kc * 32 + lk);
        float nj[2];
        #pragma unroll
        for (int n = 0; n < 2; ++n) nj[n] = nrm[jw + n * 16 + lr];

        __builtin_amdgcn_sched_barrier(0);
        // Prefetch tile t+1 -> other buffer (stays in flight through compute).
        if (t + 1 < JTPB) {
            #pragma unroll
            for (int r = 0; r < 8; ++r)
                gld_lds16(W + (size_t)(j0t + 64 + pj[r]) * NN + i0 + pc[r],
                          &wlds[cb ^ 1][r * 1024 + wave * 256]);
        }
        __builtin_amdgcn_sched_barrier(0);

        // Gram MFMA: wave tile 64(i) x 32(j), K=128.
        f32x4 acc[4][2];
        #pragma unroll
        for (int m = 0; m < 4; ++m)
            #pragma unroll
            for (int n = 0; n < 2; ++n) acc[m][n] = (f32x4){0.f, 0.f, 0.f, 0.f};
        #pragma unroll
        for (int kc = 0; kc < 4; ++kc)
            #pragma unroll
            for (int m = 0; m < 4; ++m)
                #pragma unroll
                for (int n = 0; n < 2; ++n)
                    acc[m][n] = __builtin_amdgcn_mfma_f32_16x16x32_bf16(
                        af[kc][m], bf[kc][n], acc[m][n], 0, 0, 0);

        // Epilogue: W^T from LDS (swizzled), dist, accumulate.
        #pragma unroll
        for (int m = 0; m < 4; ++m) {
            #pragma unroll
            for (int n = 0; n < 2; ++n) {
                const int jp = wCol * 32 + n * 16 + lr;
                const int c0 = wRow * 16 + m * 4 + hi;
                const f32x4 w4 = *reinterpret_cast<const f32x4*>(
                    &wlds[cb][jp * 128 + ((c0 ^ (jp & 7)) * 4)]);
                #pragma unroll
                for (int r = 0; r < 4; ++r) {
                    float sq = ni4[m][r] + nj[n] - 2.0f * acc[m][n][r];
                    sq = fmaxf(sq, 0.0f);
                    float d = sqrtf(sq);
                    sW  += w4[r];
                    sDW += w4[r] * d;
                    dmax = fmaxf(dmax, d);
                }
            }
        }
        // Drains this wave's prefetch (vmcnt 0) + barrier: buf cb^1 ready,
        // and everyone is done reading buf cb before it's overwritten.
        __syncthreads();
    }

    #pragma unroll
    for (int m = 32; m; m >>= 1) {
        sW  += __shfl_xor(sW, m);
        sDW += __shfl_xor(sDW, m);
        dmax = fmaxf(dmax, __shfl_xor(dmax, m));
    }
    if (lane == 0) { sw_s[wave] = sW; sdw_s[wave] = sDW; dm_s[wave] = dmax; }
    __syncthreads();
    if (threadIdx.x == 0) {
        float SW = 0.f, SDW = 0.f, DM = 0.f;
        #pragma unroll
        for (int k = 0; k < 4; ++k) {
            SW += sw_s[k]; SDW += sdw_s[k]; DM = fmaxf(DM, dm_s[k]);
        }
        float4 p; p.x = SW; p.y = SDW; p.z = DM; p.w = 0.f;
        part[blockIdx.y * gridDim.x + blockIdx.x] = p;
    }
}

// Single block: reduce per-block partials in fp64, emit the loss.
__global__ __launch_bounds__(512)
void reduce_kernel(const float4* __restrict__ part, int nblk,
                   float* __restrict__ out) {
    const int tid = threadIdx.x;
    double sW = 0.0, sDW = 0.0;
    float dmax = 0.f;
    for (int idx = tid; idx < nblk; idx += 512) {
        float4 p = part[idx];
        sW += (double)p.x; sDW += (double)p.y; dmax = fmaxf(dmax, p.z);
    }
    #pragma unroll
    for (int m = 32; m; m >>= 1) {
        sW  += __shfl_xor(sW, m);
        sDW += __shfl_xor(sDW, m);
        dmax = fmaxf(dmax, __shfl_xor(dmax, m));
    }
    __shared__ double sw_s[8], sdw_s[8];
    __shared__ float dm_s[8];
    const int w = tid >> 6, l = tid & 63;
    if (l == 0) { sw_s[w] = sW; sdw_s[w] = sDW; dm_s[w] = dmax; }
    __syncthreads();
    if (tid == 0) {
        double SW = 0.0, SDW = 0.0; float DM = 0.f;
        #pragma unroll
        for (int k = 0; k < 8; ++k) {
            SW += sw_s[k]; SDW += sdw_s[k]; DM = fmaxf(DM, dm_s[k]);
        }
        out[0] = (float)((SW - SDW / (double)DM) / ((double)NN * (double)NN));
    }
}

extern "C" void kernel_launch(void* const* d_in, const int* in_sizes, int n_in,
                              void* d_out, int out_size, void* d_ws, size_t ws_size,
                              hipStream_t stream) {
    const float* emb = (const float*)d_in[0];
    const float* W   = (const float*)d_in[1];
    float* out = (float*)d_out;

    char* ws = (char*)d_ws;
    float4* part        = (float4*)ws;                               // 8 KB (512 x 16B)
    unsigned short* ebf = (unsigned short*)(ws + 16384);             // 2 MB bf16 emb
    float* nrm          = (float*)(ws + 16384 + (size_t)NN * DD * 2);// 32 KB norms

    prep_kernel<<<NN / 4, 256, 0, stream>>>(emb, ebf, nrm);
    dim3 grid(NN / (64 * JTPB), NN / 128);   // 8 x 64 = 512 blocks (2/CU)
    gram_kernel<<<grid, 256, 0, stream>>>(ebf, nrm, W, part);
    reduce_kernel<<<1, 512, 0, stream>>>(part, grid.x * grid.y, out);
}